// Round 10
// baseline (640.298 us; speedup 1.0000x reference)
//
#include <hip/hip_runtime.h>
#include <math.h>

#define BATCH 256
#define T 1024
#define IN 19
#define H 128

// tanh via v_exp_f32: tanh(x)=sign(x)*(1-2/(exp(2|x|)+1)); exact to ~1e-7.
__device__ __forceinline__ float fast_tanh(float x) {
    float ax = fabsf(x);
    float e  = __expf(2.0f * ax);
    float r  = 1.0f - 2.0f / (e + 1.0f);
    return copysignf(r, x);
}

// DPP cross-lane move (VALU-only, no LDS pipe).
template <int CTRL>
__device__ __forceinline__ float dppf(float v) {
    return __int_as_float(__builtin_amdgcn_update_dpp(
        0, __float_as_int(v), CTRL, 0xF, 0xF, true));
}
#define XOR1 0xB1   // quad_perm [1,0,3,2]  : lane ^= 1
#define XOR2 0x4E   // quad_perm [2,3,0,1]  : lane ^= 2
#define XOR8 0x128  // row_ror:8            : lane ^= 8 (within 16-lane row)

// Lightweight barrier: waits LDS only (NO vmcnt drain). The lgkmcnt(0) also
// retires P's end-of-interval ds_reads, so registers loaded at interval j-1
// are valid VALU inputs at interval j.
__device__ __forceinline__ void sync_fast() {
    asm volatile("s_waitcnt lgkmcnt(0)" ::: "memory");
    __builtin_amdgcn_s_barrier();
    asm volatile("" ::: "memory");
}

// Padded LDS offset for hidden unit u: 16-float slices at stride 20.
__device__ __forceinline__ int uoff(int u) { return (u >> 4) * 20 + (u & 15); }

// ---------------------------------------------------------------------------
// Single fused kernel. 256 blocks x 512 threads (8 waves, 2/SIMD, 1 block/CU).
// Interval j roles:
//   S0 (tid   0..127): h0_j = tanh(proj0_j + Whh0.h0_{j-1})           [serial]
//   P  (tid 128..383): COMPUTE B_{j-2} from regs loaded at interval j-1
//                      (pure VALU at interval start -> no post-barrier LDS
//                      contention); proj0_{j+1} (waves 4-5); then LOAD the
//                      h0_{j-1} slice (stable slot, written last interval)
//                      into the SINGLE reg buffer for next interval.
//   S1 (tid 384..511): h1_{j-4} = tanh(B_{j-4} + Whh1.h1_{j-5})       [serial]
// vs R5/R9 (546us): P's 16 post-barrier ds_read_b128 move to pre-barrier
// (LDS queue at interval start 40->24 instrs; S0's data arrives sooner).
// vs R6 (failed): SINGLE buffer (+16 floats, not +32 -> no spill); compute-
// before-load makes the WAR safe in-order; loads target the stable
// one-interval-old slot (no race with S0's same-interval write).
// Ring audit: P reads h0_{j-1} slot (j+3)&3 at END of interval j (written
// interval j-1, next overwrite j+3: stable). B_{j-2} -> slot (j+2)&3; S1
// reads B_t at interval t+4 (written t+2, overwritten t+4... at interval
// t+4 by B_{t+2}? no: slot t&3 overwritten by B_{t+4} at interval t+6 -
// read at t+4 safe). Garbage B_{-2}(slot2,@j0)/B_{-1}(slot3,@j1) dead:
// S1's first reads B_0@j4(s0), B_1@j5(s1), B_2@j6(s2,w@j4), B_3@j7(s3,w@j5).
// All groups execute exactly 1029 barriers (init + intervals 0..1027).
// ---------------------------------------------------------------------------
__global__ __launch_bounds__(512)
__attribute__((amdgpu_waves_per_eu(2, 2)))
void fused_rnn(const float* __restrict__ x,      // [B,T,IN]
               const float* __restrict__ Wih0,   // [H,IN]
               const float* __restrict__ Whh0,   // [H,H]
               const float* __restrict__ bih0,
               const float* __restrict__ bhh0,
               const float* __restrict__ Wih1,   // [H,H]
               const float* __restrict__ Whh1,   // [H,H]
               const float* __restrict__ bih1,
               const float* __restrict__ bhh1,
               float* __restrict__ out) {        // [B,T,H]
    const int b   = blockIdx.x;
    const int tid = threadIdx.x;

    __shared__ __align__(16) float h0ring[4][160];
    __shared__ __align__(16) float h1ring[4][160];
    __shared__ __align__(16) float Bring[4][H];
    __shared__ __align__(16) float projring[4][H];   // proj0 for step k at [k&3]
    // x chunks: 8 steps x 19 floats, stride 20. Chunk c holds rows 8c+1..8c+8.
    __shared__ __align__(16) float xbuf[2][8 * 20];

    if (tid < 128) {
        // =================== S0 (pure recurrence) ===================
        __builtin_amdgcn_s_setprio(1);
        const bool b0 = tid & 1, b1 = tid & 2, b2 = tid & 8;
        const int s    = (tid & 3) | ((tid & 8) >> 1);          // slice 0..7
        const int G    = (tid >> 4) * 2 + ((tid >> 2) & 1);     // group 0..15
        const int ub   = G * 8;
        const int ufin = ub + (b0 ? 4 : 0) + (b1 ? 2 : 0) + (b2 ? 1 : 0);

        float wA[8][16];
#pragma unroll
        for (int u = 0; u < 8; ++u) {
            const float* wr = Whh0 + (size_t)(ub + u) * H + s * 16;
#pragma unroll
            for (int c = 0; c < 16; c += 4) {
                float4 v = *(const float4*)&wr[c];
                wA[u][c] = v.x; wA[u][c+1] = v.y; wA[u][c+2] = v.z; wA[u][c+3] = v.w;
            }
        }
        // prologue: proj_0 self-computed (P's ring starts at proj_1)
        {
            const float* wr = Wih0 + ufin * IN;
            const float* xr = x + (size_t)b * T * IN;   // row 0
            float acc = bih0[ufin] + bhh0[ufin];
#pragma unroll
            for (int f = 0; f < IN; ++f) acc = fmaf(xr[f], wr[f], acc);
            projring[0][ufin] = acc;
        }
        h0ring[3][uoff(ufin)] = 0.0f;   // h0_{-1}
        sync_fast();                     // init barrier

        const int so = s * 20;
        const int wo = uoff(ufin);
        for (int ko = 0; ko < T; ko += 8) {
#pragma unroll
            for (int j = 0; j < 8; ++j) {
                const float* hp = &h0ring[(j + 3) & 3][so];
                float pcur = projring[j & 3][ufin];
                float d0=0,d1=0,d2=0,d3=0,d4=0,d5=0,d6=0,d7=0;
#pragma unroll
                for (int c = 0; c < 16; c += 4) {
                    float4 hv = *(const float4*)&hp[c];
                    d0 = fmaf(wA[0][c],hv.x,d0); d0 = fmaf(wA[0][c+1],hv.y,d0); d0 = fmaf(wA[0][c+2],hv.z,d0); d0 = fmaf(wA[0][c+3],hv.w,d0);
                    d1 = fmaf(wA[1][c],hv.x,d1); d1 = fmaf(wA[1][c+1],hv.y,d1); d1 = fmaf(wA[1][c+2],hv.z,d1); d1 = fmaf(wA[1][c+3],hv.w,d1);
                    d2 = fmaf(wA[2][c],hv.x,d2); d2 = fmaf(wA[2][c+1],hv.y,d2); d2 = fmaf(wA[2][c+2],hv.z,d2); d2 = fmaf(wA[2][c+3],hv.w,d2);
                    d3 = fmaf(wA[3][c],hv.x,d3); d3 = fmaf(wA[3][c+1],hv.y,d3); d3 = fmaf(wA[3][c+2],hv.z,d3); d3 = fmaf(wA[3][c+3],hv.w,d3);
                    d4 = fmaf(wA[4][c],hv.x,d4); d4 = fmaf(wA[4][c+1],hv.y,d4); d4 = fmaf(wA[4][c+2],hv.z,d4); d4 = fmaf(wA[4][c+3],hv.w,d4);
                    d5 = fmaf(wA[5][c],hv.x,d5); d5 = fmaf(wA[5][c+1],hv.y,d5); d5 = fmaf(wA[5][c+2],hv.z,d5); d5 = fmaf(wA[5][c+3],hv.w,d5);
                    d6 = fmaf(wA[6][c],hv.x,d6); d6 = fmaf(wA[6][c+1],hv.y,d6); d6 = fmaf(wA[6][c+2],hv.z,d6); d6 = fmaf(wA[6][c+3],hv.w,d6);
                    d7 = fmaf(wA[7][c],hv.x,d7); d7 = fmaf(wA[7][c+1],hv.y,d7); d7 = fmaf(wA[7][c+2],hv.z,d7); d7 = fmaf(wA[7][c+3],hv.w,d7);
                }
                float e0 = (b0 ? d4 : d0) + dppf<XOR1>(b0 ? d0 : d4);
                float e1 = (b0 ? d5 : d1) + dppf<XOR1>(b0 ? d1 : d5);
                float e2 = (b0 ? d6 : d2) + dppf<XOR1>(b0 ? d2 : d6);
                float e3 = (b0 ? d7 : d3) + dppf<XOR1>(b0 ? d3 : d7);
                float g0 = (b1 ? e2 : e0) + dppf<XOR2>(b1 ? e0 : e2);
                float g1 = (b1 ? e3 : e1) + dppf<XOR2>(b1 ? e1 : e3);
                float f  = (b2 ? g1 : g0) + dppf<XOR8>(b2 ? g0 : g1);
                h0ring[j & 3][wo] = fast_tanh(pcur + f);
                sync_fast();
            }
        }
        sync_fast();   // interval 1024
        sync_fast();   // interval 1025
        sync_fast();   // interval 1026
        sync_fast();   // interval 1027
    } else if (tid < 384) {
        // ========== P (pipelined B-projection + layer-0 input proj) =========
        const int p  = tid - 128;
        const bool b0 = p & 1, b1 = p & 2;
        const int s    = (p & 3) | ((p & 8) >> 1);            // slice 0..7
        const int Gp   = (p >> 4) * 2 + ((p >> 2) & 1);       // group 0..31
        const int ub   = Gp * 4;
        const int ufin = ub + (b0 ? 2 : 0) + (b1 ? 1 : 0);

        float wP[4][16];
#pragma unroll
        for (int u = 0; u < 4; ++u) {
            const float* wr = Wih1 + (size_t)(ub + u) * H + s * 16;
#pragma unroll
            for (int c = 0; c < 16; c += 4) {
                float4 v = *(const float4*)&wr[c];
                wP[u][c] = v.x; wP[u][c+1] = v.y; wP[u][c+2] = v.z; wP[u][c+3] = v.w;
            }
        }
        const float biasP = bih1[ufin] + bhh1[ufin];

        // ---- proj duty: waves 4-5 (p>=128), unit = p-128 ----
        const bool hasProj = (p >= 128);
        const int pu = p - 128;                        // proj unit 0..127
        float wIP[20];
        float biasPr = 0.0f;
        const float* xsrc = x + (size_t)b * T * IN + IN;   // row 1 base
        const int idx0  = pu;
        const int idx1  = pu + 128;
        const bool v1   = hasProj && (pu < 24);
        const int slot0 = hasProj ? ((idx0 / IN) * 20 + idx0 % IN) : 0;
        const int slot1 = hasProj ? ((idx1 / IN) * 20 + idx1 % IN) : 0;
        const int XMAX  = (T - 1) * IN - 1;                // last elem rel to xsrc
        float xr0 = 0.0f, xr1 = 0.0f;

        if (hasProj) {
            const float* wr = Wih0 + (size_t)pu * IN;
#pragma unroll
            for (int f = 0; f < IN; ++f) wIP[f] = wr[f];
            wIP[19] = 0.0f;
            biasPr = bih0[pu] + bhh0[pu];
            if (pu < 8) { xbuf[0][pu * 20 + 19] = 0.0f; xbuf[1][pu * 20 + 19] = 0.0f; }
            xbuf[0][slot0] = xsrc[idx0];
            if (v1) xbuf[0][slot1] = xsrc[idx1];
            xr0 = xsrc[152 + idx0];
            if (v1) xr1 = xsrc[152 + idx1];
        }

        // single pipeline buffer: h0 slice consumed at interval j, loaded at
        // the END of interval j-1 (compute-before-load makes WAR safe).
        float4 z4 = {0.0f, 0.0f, 0.0f, 0.0f};
        float4 hb0 = z4, hb1 = z4, hb2 = z4, hb3 = z4;

        sync_fast();   // init barrier

// B-dot + reduce + conditional Bring write from float4 regs hb0..hb3.
#define P_BCOMP(BSLOT)                                                                \
        {                                                                             \
            float d0=0,d1=0,d2=0,d3=0;                                                \
            d0 = fmaf(wP[0][0],  hb0.x, d0); d0 = fmaf(wP[0][1],  hb0.y, d0);         \
            d0 = fmaf(wP[0][2],  hb0.z, d0); d0 = fmaf(wP[0][3],  hb0.w, d0);         \
            d1 = fmaf(wP[1][0],  hb0.x, d1); d1 = fmaf(wP[1][1],  hb0.y, d1);         \
            d1 = fmaf(wP[1][2],  hb0.z, d1); d1 = fmaf(wP[1][3],  hb0.w, d1);         \
            d2 = fmaf(wP[2][0],  hb0.x, d2); d2 = fmaf(wP[2][1],  hb0.y, d2);         \
            d2 = fmaf(wP[2][2],  hb0.z, d2); d2 = fmaf(wP[2][3],  hb0.w, d2);         \
            d3 = fmaf(wP[3][0],  hb0.x, d3); d3 = fmaf(wP[3][1],  hb0.y, d3);         \
            d3 = fmaf(wP[3][2],  hb0.z, d3); d3 = fmaf(wP[3][3],  hb0.w, d3);         \
            d0 = fmaf(wP[0][4],  hb1.x, d0); d0 = fmaf(wP[0][5],  hb1.y, d0);         \
            d0 = fmaf(wP[0][6],  hb1.z, d0); d0 = fmaf(wP[0][7],  hb1.w, d0);         \
            d1 = fmaf(wP[1][4],  hb1.x, d1); d1 = fmaf(wP[1][5],  hb1.y, d1);         \
            d1 = fmaf(wP[1][6],  hb1.z, d1); d1 = fmaf(wP[1][7],  hb1.w, d1);         \
            d2 = fmaf(wP[2][4],  hb1.x, d2); d2 = fmaf(wP[2][5],  hb1.y, d2);         \
            d2 = fmaf(wP[2][6],  hb1.z, d2); d2 = fmaf(wP[2][7],  hb1.w, d2);         \
            d3 = fmaf(wP[3][4],  hb1.x, d3); d3 = fmaf(wP[3][5],  hb1.y, d3);         \
            d3 = fmaf(wP[3][6],  hb1.z, d3); d3 = fmaf(wP[3][7],  hb1.w, d3);         \
            d0 = fmaf(wP[0][8],  hb2.x, d0); d0 = fmaf(wP[0][9],  hb2.y, d0);         \
            d0 = fmaf(wP[0][10], hb2.z, d0); d0 = fmaf(wP[0][11], hb2.w, d0);         \
            d1 = fmaf(wP[1][8],  hb2.x, d1); d1 = fmaf(wP[1][9],  hb2.y, d1);         \
            d1 = fmaf(wP[1][10], hb2.z, d1); d1 = fmaf(wP[1][11], hb2.w, d1);         \
            d2 = fmaf(wP[2][8],  hb2.x, d2); d2 = fmaf(wP[2][9],  hb2.y, d2);         \
            d2 = fmaf(wP[2][10], hb2.z, d2); d2 = fmaf(wP[2][11], hb2.w, d2);         \
            d3 = fmaf(wP[3][8],  hb2.x, d3); d3 = fmaf(wP[3][9],  hb2.y, d3);         \
            d3 = fmaf(wP[3][10], hb2.z, d3); d3 = fmaf(wP[3][11], hb2.w, d3);         \
            d0 = fmaf(wP[0][12], hb3.x, d0); d0 = fmaf(wP[0][13], hb3.y, d0);         \
            d0 = fmaf(wP[0][14], hb3.z, d0); d0 = fmaf(wP[0][15], hb3.w, d0);         \
            d1 = fmaf(wP[1][12], hb3.x, d1); d1 = fmaf(wP[1][13], hb3.y, d1);         \
            d1 = fmaf(wP[1][14], hb3.z, d1); d1 = fmaf(wP[1][15], hb3.w, d1);         \
            d2 = fmaf(wP[2][12], hb3.x, d2); d2 = fmaf(wP[2][13], hb3.y, d2);         \
            d2 = fmaf(wP[2][14], hb3.z, d2); d2 = fmaf(wP[2][15], hb3.w, d2);         \
            d3 = fmaf(wP[3][12], hb3.x, d3); d3 = fmaf(wP[3][13], hb3.y, d3);         \
            d3 = fmaf(wP[3][14], hb3.z, d3); d3 = fmaf(wP[3][15], hb3.w, d3);         \
            float e0 = (b0 ? d2 : d0) + dppf<XOR1>(b0 ? d0 : d2);                     \
            float e1 = (b0 ? d3 : d1) + dppf<XOR1>(b0 ? d1 : d3);                     \
            float g  = (b1 ? e1 : e0) + dppf<XOR2>(b1 ? e0 : e1);                     \
            g += dppf<XOR8>(g);                                                       \
            if (!(p & 8)) Bring[BSLOT][ufin] = g + biasP;                             \
        }

        const int so = s * 20;
        for (int ko = 0; ko < T; ko += 8) {
            const int cb = (ko >> 3) & 1;
#pragma unroll
            for (int jj = 0; jj < 8; ++jj) {
                // ---- COMPUTE B_{j-2} from regs (pure VALU, post-barrier) ----
                P_BCOMP(((jj + 2) & 3))
                // ---- ISSUE: load h0_{j-1} (slot (jj+3)&3, stable) ----
                {
                    const float* hp = &h0ring[(jj + 3) & 3][so];
                    hb0 = *(const float4*)&hp[0];  hb1 = *(const float4*)&hp[4];
                    hb2 = *(const float4*)&hp[8];  hb3 = *(const float4*)&hp[12];
                }
                // ---- proj0_{j+1} from x row jj of current chunk ----
                if (hasProj) {
                    const float* xp = &xbuf[cb][jj * 20];
                    float4 xv0 = *(const float4*)&xp[0];
                    float4 xv1 = *(const float4*)&xp[4];
                    float4 xv2 = *(const float4*)&xp[8];
                    float4 xv3 = *(const float4*)&xp[12];
                    float4 xv4 = *(const float4*)&xp[16];   // .w = pad
                    float p0 = biasPr, p1 = 0.0f;
                    p0 = fmaf(xv0.x, wIP[0],  p0); p1 = fmaf(xv0.y, wIP[1],  p1);
                    p0 = fmaf(xv0.z, wIP[2],  p0); p1 = fmaf(xv0.w, wIP[3],  p1);
                    p0 = fmaf(xv1.x, wIP[4],  p0); p1 = fmaf(xv1.y, wIP[5],  p1);
                    p0 = fmaf(xv1.z, wIP[6],  p0); p1 = fmaf(xv1.w, wIP[7],  p1);
                    p0 = fmaf(xv2.x, wIP[8],  p0); p1 = fmaf(xv2.y, wIP[9],  p1);
                    p0 = fmaf(xv2.z, wIP[10], p0); p1 = fmaf(xv2.w, wIP[11], p1);
                    p0 = fmaf(xv3.x, wIP[12], p0); p1 = fmaf(xv3.y, wIP[13], p1);
                    p0 = fmaf(xv3.z, wIP[14], p0); p1 = fmaf(xv3.w, wIP[15], p1);
                    p0 = fmaf(xv4.x, wIP[16], p0); p1 = fmaf(xv4.y, wIP[17], p1);
                    p0 = fmaf(xv4.z, wIP[18], p0); p1 = fmaf(xv4.w, wIP[19], p1);
                    projring[(jj + 1) & 3][pu] = p0 + p1;
                    if (jj == 7) {
                        // publish chunk c+1 (pre-barrier), fetch chunk c+2
                        float* xd = xbuf[cb ^ 1];
                        xd[slot0] = xr0;
                        if (v1) xd[slot1] = xr1;
                        const int c2 = (ko >> 3) + 2;
                        int o0 = 152 * c2 + idx0; o0 = o0 > XMAX ? XMAX : o0;
                        int o1 = 152 * c2 + idx1; o1 = o1 > XMAX ? XMAX : o1;
                        xr0 = xsrc[o0];
                        if (v1) xr1 = xsrc[o1];
                    }
                }
                sync_fast();
            }
        }
        // ---- epilogue ----
        // interval 1024: B_1022 from h_buf (h0_1022) -> slot 2; then load
        // h0_1023 (slot 3, written at interval 1023, stable).
        P_BCOMP(2)
        {
            const float* hp = &h0ring[3][so];
            hb0 = *(const float4*)&hp[0];  hb1 = *(const float4*)&hp[4];
            hb2 = *(const float4*)&hp[8];  hb3 = *(const float4*)&hp[12];
        }
        sync_fast();   // interval 1024
        // interval 1025: B_1023 from h0_1023 -> slot 3.
        P_BCOMP(3)
        sync_fast();   // interval 1025
        sync_fast();   // interval 1026
        sync_fast();   // interval 1027
#undef P_BCOMP
    } else {
        // =================== S1 (h1_{j-4} at interval j) ===================
        __builtin_amdgcn_s_setprio(1);
        const int w  = tid - 384;
        const bool b0 = w & 1, b1 = w & 2, b2 = w & 8;
        const int s    = (w & 3) | ((w & 8) >> 1);
        const int G    = (w >> 4) * 2 + ((w >> 2) & 1);
        const int ub   = G * 8;
        const int ufin = ub + (b0 ? 4 : 0) + (b1 ? 2 : 0) + (b2 ? 1 : 0);

        float wA[8][16];
#pragma unroll
        for (int u = 0; u < 8; ++u) {
            const float* wr = Whh1 + (size_t)(ub + u) * H + s * 16;
#pragma unroll
            for (int c = 0; c < 16; c += 4) {
                float4 v = *(const float4*)&wr[c];
                wA[u][c] = v.x; wA[u][c+1] = v.y; wA[u][c+2] = v.z; wA[u][c+3] = v.w;
            }
        }
        float* orow = out + (size_t)b * T * H + ufin;
        float sbuf[8];

        h1ring[3][uoff(ufin)] = 0.0f;   // h1_{-1}
        sync_fast();   // init barrier
        sync_fast();   // interval 0
        sync_fast();   // interval 1
        sync_fast();   // interval 2
        sync_fast();   // interval 3

        const int so = s * 20;
        const int wo = uoff(ufin);
        for (int ko = 4; ko < 1028; ko += 8) {
#pragma unroll
            for (int j = 0; j < 8; ++j) {
                // interval ko+j: t = ko+j-4. h1_{t-1} slot (j+3)&3;
                // B_t slot j&3 (written by P at interval t+2 = ko+j-2).
                const float* hp = &h1ring[(j + 3) & 3][so];
                float Bg = Bring[j & 3][ufin];
                float d0=0,d1=0,d2=0,d3=0,d4=0,d5=0,d6=0,d7=0;
#pragma unroll
                for (int c = 0; c < 16; c += 4) {
                    float4 hv = *(const float4*)&hp[c];
                    d0 = fmaf(wA[0][c],hv.x,d0); d0 = fmaf(wA[0][c+1],hv.y,d0); d0 = fmaf(wA[0][c+2],hv.z,d0); d0 = fmaf(wA[0][c+3],hv.w,d0);
                    d1 = fmaf(wA[1][c],hv.x,d1); d1 = fmaf(wA[1][c+1],hv.y,d1); d1 = fmaf(wA[1][c+2],hv.z,d1); d1 = fmaf(wA[1][c+3],hv.w,d1);
                    d2 = fmaf(wA[2][c],hv.x,d2); d2 = fmaf(wA[2][c+1],hv.y,d2); d2 = fmaf(wA[2][c+2],hv.z,d2); d2 = fmaf(wA[2][c+3],hv.w,d2);
                    d3 = fmaf(wA[3][c],hv.x,d3); d3 = fmaf(wA[3][c+1],hv.y,d3); d3 = fmaf(wA[3][c+2],hv.z,d3); d3 = fmaf(wA[3][c+3],hv.w,d3);
                    d4 = fmaf(wA[4][c],hv.x,d4); d4 = fmaf(wA[4][c+1],hv.y,d4); d4 = fmaf(wA[4][c+2],hv.z,d4); d4 = fmaf(wA[4][c+3],hv.w,d4);
                    d5 = fmaf(wA[5][c],hv.x,d5); d5 = fmaf(wA[5][c+1],hv.y,d5); d5 = fmaf(wA[5][c+2],hv.z,d5); d5 = fmaf(wA[5][c+3],hv.w,d5);
                    d6 = fmaf(wA[6][c],hv.x,d6); d6 = fmaf(wA[6][c+1],hv.y,d6); d6 = fmaf(wA[6][c+2],hv.z,d6); d6 = fmaf(wA[6][c+3],hv.w,d6);
                    d7 = fmaf(wA[7][c],hv.x,d7); d7 = fmaf(wA[7][c+1],hv.y,d7); d7 = fmaf(wA[7][c+2],hv.z,d7); d7 = fmaf(wA[7][c+3],hv.w,d7);
                }
                float e0 = (b0 ? d4 : d0) + dppf<XOR1>(b0 ? d0 : d4);
                float e1 = (b0 ? d5 : d1) + dppf<XOR1>(b0 ? d1 : d5);
                float e2 = (b0 ? d6 : d2) + dppf<XOR1>(b0 ? d2 : d6);
                float e3 = (b0 ? d7 : d3) + dppf<XOR1>(b0 ? d3 : d7);
                float g0 = (b1 ? e2 : e0) + dppf<XOR2>(b1 ? e0 : e2);
                float g1 = (b1 ? e3 : e1) + dppf<XOR2>(b1 ? e1 : e3);
                float f  = (b2 ? g1 : g0) + dppf<XOR8>(b2 ? g0 : g1);
                float h1v = fast_tanh(Bg + f);
                h1ring[j & 3][wo] = h1v;
                sbuf[j] = h1v;
                if (j == 7) {                  // burst-write t = ko-4 .. ko+3
                    const int t0 = ko - 4;
#pragma unroll
                    for (int i = 0; i < 8; ++i)
                        orow[(size_t)(t0 + i) * H] = sbuf[i];
                }
                sync_fast();
            }
        }
        // no trailing barriers needed for S1 (last interval is 1027)
    }
}

// ---------------------------------------------------------------------------
extern "C" void kernel_launch(void* const* d_in, const int* in_sizes, int n_in,
                              void* d_out, int out_size, void* d_ws, size_t ws_size,
                              hipStream_t stream) {
    const float* x     = (const float*)d_in[0];
    const float* W_ih0 = (const float*)d_in[1];
    const float* W_hh0 = (const float*)d_in[2];
    const float* b_ih0 = (const float*)d_in[3];
    const float* b_hh0 = (const float*)d_in[4];
    const float* W_ih1 = (const float*)d_in[5];
    const float* W_hh1 = (const float*)d_in[6];
    const float* b_ih1 = (const float*)d_in[7];
    const float* b_hh1 = (const float*)d_in[8];

    float* out = (float*)d_out;

    fused_rnn<<<BATCH, 512, 0, stream>>>(x, W_ih0, W_hh0, b_ih0, b_hh0,
                                         W_ih1, W_hh1, b_ih1, b_hh1, out);
}